// Round 9
// baseline (257.599 us; speedup 1.0000x reference)
//
#include <hip/hip_runtime.h>
#include <hip/hip_bf16.h>
#include <hip/hip_fp16.h>

// Problem constants (fixed by setup_inputs)
#define NQ   5440
#define NB   8
#define DIM  256
#define NH   8
#define CHN  32
#define NLV  4
#define NPT  4
#define MTOT (NB * NQ)   // 43520

typedef __attribute__((ext_vector_type(8))) short s16x8;   // 8 x 16-bit (4 VGPRs)
typedef __attribute__((ext_vector_type(4))) float f32x4;
typedef unsigned short ushort_t;

// bf16 weight-buffer segment offsets (elements): [W_val | W_off | W_attn | W_out]
#define WVAL 0
#define WOFF 65536
#define WATT 131072
#define WOUT 163840
#define WTOT 229376

__device__ __forceinline__ short f2bf(float x) {
    union { __hip_bfloat16 b; short s; } u;
    u.b = __float2bfloat16(x);
    return u.s;
}

// async 16B global->LDS copy; LDS dst = wave-uniform base + lane*16
__device__ __forceinline__ void gload_lds16(const void* g, void* l) {
    __builtin_amdgcn_global_load_lds(
        (const __attribute__((address_space(1))) unsigned int*)g,
        (__attribute__((address_space(3))) unsigned int*)l, 16, 0, 0);
}

__device__ __forceinline__ void cvt8b(const float* s, ushort_t* d) {
    f32x4 a = *(const f32x4*)s, b = *(const f32x4*)(s + 4);
    s16x8 v;
#pragma unroll
    for (int e = 0; e < 4; ++e) { v[e] = f2bf(a[e]); v[e + 4] = f2bf(b[e]); }
    *(s16x8*)d = v;
}

// one-time fp32 -> bf16 of the 4 weight matrices (0.9 MB read, ~2 us)
__global__ __launch_bounds__(256) void cvt_weights(const float* __restrict__ wv,
                                                   const float* __restrict__ wo,
                                                   const float* __restrict__ wa,
                                                   const float* __restrict__ wu,
                                                   ushort_t* __restrict__ wb) {
    const int i = (blockIdx.x * 256 + threadIdx.x) * 8;
    if (i >= WTOT) return;
    const float* src;
    int off;
    if (i < WOFF)      { src = wv; off = WVAL; }
    else if (i < WATT) { src = wo; off = WOFF; }
    else if (i < WOUT) { src = wa; off = WATT; }
    else               { src = wu; off = WOUT; }
    cvt8b(src + (i - off), wb + i);
}

__device__ __forceinline__ void stC(float* p, float v) { *p = v; }
__device__ __forceinline__ void stC(__half* p, float v) { *p = __float2half(v); }
__device__ __forceinline__ void stC(ushort_t* p, float v) { *(short*)p = f2bf(v); }

// C[m, j] = sum_k A[rowBase+m, k] * Wt[j, k] + biasT[j]
// 128x128 tile, BK=64, 256 threads (2x2 waves), 4x4 16x16x32 bf16 MFMA frags.
// LDS XOR-swizzled in 16B chunks (slot (g+r)&7). HSPLIT epilogue writes the
// head-major value layout (h, n*pix, 32ch): addr = (col>>5)*MTOT*32 + row*32
// + (col&31) — same 32B-per-lane-group coalescing as the normal path.
template <typename AT, typename CT, bool HSPLIT>
__device__ __forceinline__ void gemm_core(const AT* __restrict__ A,
                                          const ushort_t* __restrict__ Wt,
                                          const float* __restrict__ biasT,
                                          CT* __restrict__ Ct, int ldC, int rowBase,
                                          int colOff) {
    __shared__ ushort_t As[128 * 64];   // 16 KB
    __shared__ ushort_t Ws[128 * 64];   // 16 KB

    const int t = threadIdx.x;
    const int lane = t & 63, w = t >> 6;
    const int wm = w >> 1, wn = w & 1;
    const int lr = lane & 15, quad = lane >> 4;

    f32x4 acc[4][4];
#pragma unroll
    for (int i = 0; i < 4; ++i)
#pragma unroll
        for (int j = 0; j < 4; ++j)
#pragma unroll
            for (int r = 0; r < 4; ++r) acc[i][j][r] = 0.f;

    for (int ks = 0; ks < 4; ++ks) {
        if (ks) __syncthreads();
#pragma unroll
        for (int i = 0; i < 4; ++i) {
            const int c = t + i * 256;          // chunk id 0..1023
            const int r = c >> 3, s = c & 7;
            const int g = (s - r) & 7;          // inverse swizzle
            const int ke = ks * 64 + g * 8;     // element k-offset
            gload_lds16(Wt + (size_t)r * DIM + ke,
                        &Ws[(size_t)(i * 256 + w * 64) * 8]);
            if constexpr (sizeof(AT) == 2) {
                gload_lds16(A + (size_t)(rowBase + r) * DIM + ke,
                            &As[(size_t)(i * 256 + w * 64) * 8]);
            } else {
                const float* pa = (const float*)A + (size_t)(rowBase + r) * DIM + ke;
                f32x4 a0 = *(const f32x4*)pa, a1 = *(const f32x4*)(pa + 4);
                s16x8 av;
#pragma unroll
                for (int e = 0; e < 4; ++e) {
                    av[e] = f2bf(a0[e]);
                    av[e + 4] = f2bf(a1[e]);
                }
                *(s16x8*)&As[(size_t)c * 8] = av;   // slot == chunk id (identity)
            }
        }
        __syncthreads();                        // drains vm+lgkm, barrier
#pragma unroll
        for (int kk = 0; kk < 64; kk += 32) {
            s16x8 afr[4], wfr[4];
            const int G = (kk >> 3) + quad;
#pragma unroll
            for (int i = 0; i < 4; ++i) {
                const int R = wm * 64 + i * 16 + lr;
                afr[i] = *(const s16x8*)&As[(R * 8 + ((G + R) & 7)) * 8];
            }
#pragma unroll
            for (int j = 0; j < 4; ++j) {
                const int R = wn * 64 + j * 16 + lr;
                wfr[j] = *(const s16x8*)&Ws[(R * 8 + ((G + R) & 7)) * 8];
            }
#pragma unroll
            for (int i = 0; i < 4; ++i)
#pragma unroll
                for (int j = 0; j < 4; ++j)
                    acc[i][j] = __builtin_amdgcn_mfma_f32_16x16x32_bf16(
                        afr[i], wfr[j], acc[i][j], 0, 0, 0);
        }
    }

    float bj[4];
#pragma unroll
    for (int j = 0; j < 4; ++j) bj[j] = biasT[wn * 64 + j * 16 + lr];
#pragma unroll
    for (int i = 0; i < 4; ++i)
#pragma unroll
        for (int r = 0; r < 4; ++r) {
            int row = rowBase + wm * 64 + i * 16 + quad * 4 + r;   // D row
#pragma unroll
            for (int j = 0; j < 4; ++j) {
                int col = wn * 64 + j * 16 + lr;                    // D col
                float v = acc[i][j][r] + bj[j];
                if constexpr (HSPLIT) {
                    const int gc = colOff + col;
                    const size_t addr =
                        ((size_t)(gc >> 5) * MTOT + row) * CHN + (gc & 31);
                    stC(&Ct[addr], v);
                } else {
                    stC(&Ct[(size_t)row * ldC + col], v);
                }
            }
        }
}

// val (2 col-tiles, head-major f16) + off (2, f16) + attn (1, f16): grid (340, 5)
__global__ __launch_bounds__(256) void gemm_fused(const float* __restrict__ inputf,
                                                  const float* __restrict__ query,
                                                  const ushort_t* __restrict__ wb,
                                                  const float* __restrict__ b_val,
                                                  const float* __restrict__ b_off,
                                                  const float* __restrict__ b_attn,
                                                  __half* __restrict__ bval,
                                                  __half* __restrict__ v_off,
                                                  __half* __restrict__ v_attn) {
    const int gy = blockIdx.y;
    const int rowBase = blockIdx.x * 128;
    if (gy < 2)
        gemm_core<float, __half, true>(inputf, wb + WVAL + (size_t)gy * 128 * DIM,
                                       b_val + gy * 128, bval, 0, rowBase, gy * 128);
    else if (gy < 4)
        gemm_core<float, __half, false>(query, wb + WOFF + (size_t)(gy - 2) * 128 * DIM,
                                        b_off + (gy - 2) * 128,
                                        v_off + (gy - 2) * 128, DIM, rowBase, 0);
    else
        gemm_core<float, __half, false>(query, wb + WATT, b_attn, v_attn, 128,
                                        rowBase, 0);
}

__global__ __launch_bounds__(256) void gemm_out(const ushort_t* __restrict__ A,
                                                const ushort_t* __restrict__ wb,
                                                const float* __restrict__ bias,
                                                float* __restrict__ C) {
    gemm_core<ushort_t, float, false>(A, wb + WOUT + (size_t)blockIdx.y * 128 * DIM,
                                      bias + blockIdx.y * 128, C + blockIdx.y * 128,
                                      DIM, blockIdx.x * 128, 0);
}

// One block per 4 queries, 128 threads. XCD-aware: batch n = blockIdx.x & 7.
// Value is head-major (h, n*pix, 32ch): pixel stride 64B, per-head planes
// contiguous (level-2/3 planes are 16KB/4KB -> L1-resident).
// Phase A (128 thr x 4 items = 512 = q4*h*l*p): coords + softmax + pixel BYTE
//   offsets (within head-plane) + packed-half2 weights -> LDS, slot = item idx.
// Phase B: thread = (q4, h, cg): 8 f16 channels per corner via uint4; 2-deep
//   explicit load pipeline (next j's id/w/corner loads issued before consuming
//   current); 4 v_pk_fma_f16 per corner; f32 flush every 4 iterations.
__global__ __launch_bounds__(128) void sample_kernel(
    const float* __restrict__ refp,            // (N, Lq, L, 2)
    const __half* __restrict__ off,            // (N*Lq, 256) f16
    const __half* __restrict__ attn,           // (N*Lq, 128) f16
    const __half* __restrict__ bval,           // (NH, N*Lin, 32) f16 head-major
    const int* __restrict__ shapes,            // (L, 2) [H, W]
    const int* __restrict__ starts,            // (L,)
    ushort_t* __restrict__ sampb)              // (N*Lq, 256) bf16
{
    const int n = blockIdx.x & 7;
    const int qBase = n * NQ + (blockIdx.x >> 3) * 4;
    const int t = threadIdx.x;

    __shared__ __align__(16) int     sidx[512][4];   // 8 KB
    __shared__ __align__(16) __half2 sww[512][4];    // 8 KB

#pragma unroll
    for (int it = 0; it < 4; ++it) {
        const int i = t + it * 128;
        const int q4 = i >> 7, hlp = i & 127;
        const int h = hlp >> 4, lp = hlp & 15, l = lp >> 2;
        const int q = qBase + q4;
        const int Wl = shapes[2 * l + 1], Hl = shapes[2 * l];
        const float Wf = (float)Wl, Hf = (float)Hl;
        const float2 rp = *(const float2*)(refp + ((size_t)q * NLV + l) * 2);
        const __half2 oo2 = ((const __half2*)off)[(size_t)q * 128 + h * 16 + lp];
        const float2 oo = __half22float2(oo2);
        const float x = (rp.x + oo.x / Wf) * Wf - 0.5f;
        const float y = (rp.y + oo.y / Hf) * Hf - 0.5f;

        float logit = __half2float(attn[(size_t)q * 128 + h * 16 + lp]);
        float m = logit;
#pragma unroll
        for (int s = 8; s >= 1; s >>= 1) m = fmaxf(m, __shfl_xor(m, s, 16));
        float e = __expf(logit - m);
        float ss = e;
#pragma unroll
        for (int s = 8; s >= 1; s >>= 1) ss += __shfl_xor(ss, s, 16);
        const float aw = e / ss;

        const float xf = floorf(x), yf = floorf(y);
        const int ix = (int)xf, iy = (int)yf;
        const float wx = x - xf, wy = y - yf;
        const int ix1 = ix + 1, iy1 = iy + 1;
        const bool bx0 = (ix >= 0) & (ix < Wl);
        const bool bx1 = (ix1 >= 0) & (ix1 < Wl);
        const bool by0 = (iy >= 0) & (iy < Hl);
        const bool by1 = (iy1 >= 0) & (iy1 < Hl);
        const int cx0 = min(max(ix, 0), Wl - 1), cx1 = min(max(ix1, 0), Wl - 1);
        const int cy0 = min(max(iy, 0), Hl - 1), cy1 = min(max(iy1, 0), Hl - 1);
        const int base = starts[l];
        int4 id;                                // byte offsets within head-plane
        id.x = (base + cy0 * Wl + cx0) << 6;    // pixel stride 64B
        id.y = (base + cy0 * Wl + cx1) << 6;
        id.z = (base + cy1 * Wl + cx0) << 6;
        id.w = (base + cy1 * Wl + cx1) << 6;
        __half2 wp[4];
        wp[0] = __float2half2_rn((bx0 && by0) ? aw * (1.f - wx) * (1.f - wy) : 0.f);
        wp[1] = __float2half2_rn((bx1 && by0) ? aw * wx * (1.f - wy) : 0.f);
        wp[2] = __float2half2_rn((bx0 && by1) ? aw * (1.f - wx) * wy : 0.f);
        wp[3] = __float2half2_rn((bx1 && by1) ? aw * wx * wy : 0.f);
        *(int4*)sidx[i] = id;
        *(uint4*)&sww[i][0] = *(uint4*)wp;
    }
    __syncthreads();

    const int q4 = t >> 5, r = t & 31;
    const int h = r >> 2, cg = r & 3;           // 8 channels per thread
    const int q = qBase + q4;
    const char* vb = (const char*)bval +
                     (((size_t)h * MTOT + (size_t)n * NQ) << 6) + cg * 16;
    const int sbase = (q4 << 7) + (h << 4);

    __half2 acch[4];
    float accf[8];
#pragma unroll
    for (int e = 0; e < 4; ++e) acch[e] = __float2half2_rn(0.f);
#pragma unroll
    for (int e = 0; e < 8; ++e) accf[e] = 0.f;

    // pipeline prologue: j = 0
    int4 idA = *(const int4*)sidx[sbase + (h & 15)];
    uint4 wA = *(const uint4*)&sww[sbase + (h & 15)][0];
    uint4 uA0 = *(const uint4*)(vb + (unsigned)idA.x);
    uint4 uA1 = *(const uint4*)(vb + (unsigned)idA.y);
    uint4 uA2 = *(const uint4*)(vb + (unsigned)idA.z);
    uint4 uA3 = *(const uint4*)(vb + (unsigned)idA.w);

#pragma unroll
    for (int j = 0; j < 16; ++j) {
        // prefetch j+1 (j=15 wraps: harmless valid loads, results unused)
        const int lpn = (j + 1 + h) & 15;
        const int4 idB = *(const int4*)sidx[sbase + lpn];
        const uint4 wB = *(const uint4*)&sww[sbase + lpn][0];
        const uint4 uB0 = *(const uint4*)(vb + (unsigned)idB.x);
        const uint4 uB1 = *(const uint4*)(vb + (unsigned)idB.y);
        const uint4 uB2 = *(const uint4*)(vb + (unsigned)idB.z);
        const uint4 uB3 = *(const uint4*)(vb + (unsigned)idB.w);

        // consume j
        const __half2* wp = (const __half2*)&wA;
        const __half2* h0 = (const __half2*)&uA0;
        const __half2* h1 = (const __half2*)&uA1;
        const __half2* h2 = (const __half2*)&uA2;
        const __half2* h3 = (const __half2*)&uA3;
#pragma unroll
        for (int e = 0; e < 4; ++e) {
            acch[e] = __hfma2(h0[e], wp[0], acch[e]);
            acch[e] = __hfma2(h1[e], wp[1], acch[e]);
            acch[e] = __hfma2(h2[e], wp[2], acch[e]);
            acch[e] = __hfma2(h3[e], wp[3], acch[e]);
        }
        if ((j & 3) == 3) {
#pragma unroll
            for (int e = 0; e < 4; ++e) {
                float2 f = __half22float2(acch[e]);
                accf[2 * e] += f.x;
                accf[2 * e + 1] += f.y;
                acch[e] = __float2half2_rn(0.f);
            }
        }
        idA = idB; wA = wB;
        uA0 = uB0; uA1 = uB1; uA2 = uB2; uA3 = uB3;
    }

    s16x8 o;
#pragma unroll
    for (int e = 0; e < 8; ++e) o[e] = f2bf(accf[e]);
    *(s16x8*)(sampb + (size_t)q * DIM + h * CHN + cg * 8) = o;
}

extern "C" void kernel_launch(void* const* d_in, const int* in_sizes, int n_in,
                              void* d_out, int out_size, void* d_ws, size_t ws_size,
                              hipStream_t stream) {
    const float* query  = (const float*)d_in[0];
    const float* refp   = (const float*)d_in[1];
    const float* inputf = (const float*)d_in[2];
    const int* shapes   = (const int*)d_in[3];
    const int* starts   = (const int*)d_in[4];
    const float* W_off  = (const float*)d_in[5];
    const float* b_off  = (const float*)d_in[6];
    const float* W_attn = (const float*)d_in[7];
    const float* b_attn = (const float*)d_in[8];
    const float* W_val  = (const float*)d_in[9];
    const float* b_val  = (const float*)d_in[10];
    const float* W_out  = (const float*)d_in[11];
    const float* b_out  = (const float*)d_in[12];
    float* out = (float*)d_out;

    // workspace (bytes): wb(bf16) | bval(f16) | v_off(f16) | v_attn(f16) | sampb(bf16)
    const size_t AB = (size_t)MTOT * DIM * 2;   // 22,282,240
    char* ws = (char*)d_ws;
    ushort_t* wb     = (ushort_t*)ws;                                   // 0.46 MB
    __half*   bval   = (__half*)(ws + 512 * 1024);
    __half*   v_off  = (__half*)(ws + 512 * 1024 + AB);
    __half*   v_attn = (__half*)(ws + 512 * 1024 + 2 * AB);
    ushort_t* sampb  = (ushort_t*)(ws + 512 * 1024 + 2 * AB + AB / 2);

    cvt_weights<<<dim3(WTOT / 2048), dim3(256), 0, stream>>>(W_val, W_off, W_attn,
                                                             W_out, wb);
    gemm_fused<<<dim3(MTOT / 128, 5), dim3(256), 0, stream>>>(
        inputf, query, wb, b_val, b_off, b_attn, bval, v_off, v_attn);
    sample_kernel<<<dim3(MTOT / 4), dim3(128), 0, stream>>>(
        refp, v_off, v_attn, bval, shapes, starts, sampb);
    gemm_out<<<dim3(MTOT / 128, 2), dim3(256), 0, stream>>>(sampb, wb, b_out, out);
}